// Round 15
// baseline (121.029 us; speedup 1.0000x reference)
//
#include <hip/hip_runtime.h>
#include <stdint.h>

using short8 = __attribute__((ext_vector_type(8))) short;
using f32x4  = __attribute__((ext_vector_type(4))) float;
using u16x4  = __attribute__((ext_vector_type(4))) unsigned short;

__device__ __forceinline__ unsigned short f2bf(float f) {
    unsigned int u = __float_as_uint(f);
    unsigned int r = (u + 0x7fffu + ((u >> 16) & 1u)) >> 16;
    return (unsigned short)r;
}

// ---------------- wprep: B_all[off][col=rot*64+o][k=r*64+c] = wgt[o][c][(r-rot)&3][t(off,rot)] ----------------
__global__ __launch_bounds__(256) void k_wprep(const float* __restrict__ wgt,
                                               unsigned short* __restrict__ ball) {
    int idx = blockIdx.x * 256 + threadIdx.x;          // 589824 elems
    int k = idx & 255; int col = (idx >> 8) & 255; int j = idx >> 16;
    int rot = col >> 6, o = col & 63;
    int r = k >> 6, c = k & 63;
    int t = (j == 0) ? 0 : (1 + ((j - 1 - 2 * rot) & 7));
    float v = wgt[((o * 64 + c) * 4 + ((r - rot) & 3)) * 9 + t];
    ball[idx] = f2bf(v);
}

// ---------------- fused main: 1024 threads / 16 waves (4 waves/SIMD) ----------------
// waves = 2(M: h-row) x 8(N: rot x o-half). Traffic identical to R13 except B-reads x2 (L2-hot).
__global__ __launch_bounds__(1024) void k_main(const float* __restrict__ x,
                                               const unsigned short* __restrict__ ball,
                                               float* __restrict__ out) {
    extern __shared__ char lds[];                      // 135168 A-panel + 17408 bounce = 152576
    int d = blockIdx.x;
    int orig = (d & 7) * 32 + (d >> 3);                // XCD-chunked
    int n = orig >> 5; int h0 = (orig & 31) * 2;
    int tid = threadIdx.x;
    unsigned short* smu = (unsigned short*)(lds + 135168);   // bounce [128][68] u16

    // zero the w-halo slots (ws=0, ws=65) of the A-panel
    if (tid < 256) {
        int r4 = tid >> 6; int sp = (tid >> 5) & 1; int cc = tid & 31;
        f32x4 z = {0.f, 0.f, 0.f, 0.f};
        *(f32x4*)(lds + r4 * 33792 + (sp ? 65 * 512 : 0) + cc * 16) = z;
    }

    // stage: transpose x[n][c][r][hh][w] -> A-panel, 4 rows x 2 k-halves (1024-thread version)
    int klA = tid >> 3; int w8 = tid & 7;              // phase A: thread = (k-row, w-eighth)
#pragma unroll 1
    for (int r4 = 0; r4 < 4; r4++) {
        int hh = h0 - 1 + r4;
        bool ok = ((unsigned)hh < 64u);
#pragma unroll 1
        for (int half = 0; half < 2; half++) {
            if (ok) {
                int k = half * 128 + klA;
                int r = k >> 6, c = k & 63;
                const float* src = x + (((size_t)(n * 64 + c) * 4 + r) * 64 + hh) * 64 + w8 * 8;
#pragma unroll
                for (int i = 0; i < 2; i++) {
                    f32x4 v = *(const f32x4*)(src + i * 4);
                    u16x4 b; b[0] = f2bf(v[0]); b[1] = f2bf(v[1]);
                    b[2] = f2bf(v[2]); b[3] = f2bf(v[3]);
                    *(u16x4*)(smu + klA * 68 + w8 * 8 + i * 4) = b;
                }
            } else {
                u16x4 z = {0, 0, 0, 0};
#pragma unroll
                for (int i = 0; i < 2; i++)
                    *(u16x4*)(smu + klA * 68 + w8 * 8 + i * 4) = z;
            }
            __syncthreads();
            // phase B: repack k-major short8 chunks into swizzled A-panel (1 chunk/thread)
            {
                int w = tid & 63; int sl = tid >> 6;   // 0..15
                int key = (w + 1) & 7;
                char* prow = lds + (r4 * 66 + (w + 1)) * 512;
                int sg = half * 16 + sl;
                short8 vv;
#pragma unroll
                for (int e = 0; e < 8; e++) vv[e] = (short)smu[(sl * 8 + e) * 68 + w];
                *(short8*)(prow + ((sg ^ key) << 4)) = vv;
            }
            __syncthreads();
        }
    }

    // ---------------- main loop: 16 waves = 2M x 8N ----------------
    int wv = tid >> 6; int l = tid & 63; int l15 = l & 15; int l4 = l >> 4;
    int m = wv >> 3;                                   // h-row within pair
    int grp = wv & 7; int rot = grp >> 1;              // N-group: cols [grp*32, grp*32+32)
    int h = h0 + m;
    const char* bb = (const char*)ball;

    for (int j = 0; j < 9; j++) {
        int dy = ((0x1A901 >> (2 * j)) & 3) - 1;
        int dx = ((0x01A91 >> (2 * j)) & 3) - 1;
        int t = (j == 0) ? 0 : (1 + ((j - 1 - 2 * rot) & 7));
        int r4 = m + dy + 1;

        short8 Bf[2][8];
#pragma unroll
        for (int ct = 0; ct < 2; ct++) {
            int col = grp * 32 + ct * 16 + l15;
            const char* bp = bb + j * 131072 + col * 512 + l4 * 16;
#pragma unroll
            for (int ks = 0; ks < 8; ks++) Bf[ct][ks] = *(const short8*)(bp + ks * 64);
        }

#pragma unroll 1
        for (int mt = 0; mt < 4; mt++) {
            int ws = mt * 16 + l15 + dx + 1;           // pixel w + dx + 1
            const char* ap = lds + (r4 * 66 + ws) * 512;
            int key = ws & 7;
            short8 Af[8];
#pragma unroll
            for (int ks = 0; ks < 8; ks++) {
                int s = ks * 4 + l4;
                Af[ks] = *(const short8*)(ap + ((s ^ key) << 4));
            }
            f32x4 acc[2];
            acc[0] = (f32x4){0.f, 0.f, 0.f, 0.f};
            acc[1] = (f32x4){0.f, 0.f, 0.f, 0.f};
            __builtin_amdgcn_s_setprio(1);
#pragma unroll
            for (int ks = 0; ks < 8; ks++) {
                acc[0] = __builtin_amdgcn_mfma_f32_16x16x32_bf16(Af[ks], Bf[0][ks], acc[0], 0, 0, 0);
                acc[1] = __builtin_amdgcn_mfma_f32_16x16x32_bf16(Af[ks], Bf[1][ks], acc[1], 0, 0, 0);
            }
            __builtin_amdgcn_s_setprio(0);
            int wb = mt * 16 + 4 * l4;
#pragma unroll
            for (int ct = 0; ct < 2; ct++) {
                int o = grp * 32 + ct * 16 + l15;      // grp*32 spans (rot-consistent) col range
                int oo = o & 63;                        // o within [0,64): grp includes rot -> mask
                int idx = (((n * 576 + t * 64 + oo) * 4 + rot) * 64 + h) * 64 + wb;
                *(f32x4*)(out + idx) = acc[ct];
            }
        }
    }
}

// ---------------- fallback (ws too small): direct fp32 ----------------
__global__ __launch_bounds__(256) void k_naive(const float* __restrict__ x,
                                               const float* __restrict__ wgt,
                                               float* __restrict__ out) {
    int idx = blockIdx.x * 256 + threadIdx.x;
    if (idx >= 75497472) return;
    int w = idx & 63, h = (idx >> 6) & 63, rot = (idx >> 12) & 3;
    int chn = idx >> 14; int ch = chn % 576; int n = chn / 576;
    int t = ch >> 6, o = ch & 63;
    int dy = 0, dx = 0;
    if (t > 0) {
        int ri = (t - 1 + 2 * rot) & 7;
        dy = ((27200 >> (2 * ri)) & 3) - 1;
        dx = ((1700 >> (2 * ri)) & 3) - 1;
    }
    int hh = h + dy, ww = w + dx;
    float acc = 0.f;
    if (hh >= 0 && hh < 64 && ww >= 0 && ww < 64) {
        for (int r = 0; r < 4; r++) {
            int rr = (r - rot) & 3;
            for (int c = 0; c < 64; c++)
                acc += x[(((n * 64 + c) * 4 + r) * 64 + hh) * 64 + ww] *
                       wgt[((o * 64 + c) * 4 + rr) * 9 + t];
        }
    }
    out[idx] = acc;
}

extern "C" void kernel_launch(void* const* d_in, const int* in_sizes, int n_in,
                              void* d_out, int out_size, void* d_ws, size_t ws_size,
                              hipStream_t stream) {
    const float* x = (const float*)d_in[0];
    const float* wgt = (const float*)d_in[1];
    float* out = (float*)d_out;
    const size_t NEED = (size_t)9 * 256 * 256 * 2;     // 1,179,648 (ball only)
    if (ws_size < NEED) {
        k_naive<<<(75497472 + 255) / 256, 256, 0, stream>>>(x, wgt, out);
        return;
    }
    unsigned short* ball = (unsigned short*)d_ws;
    k_wprep<<<2304, 256, 0, stream>>>(wgt, ball);
    k_main<<<256, 1024, 152576, stream>>>(x, ball, out);
}

// Round 16
// 82.139 us; speedup vs baseline: 1.4735x; 1.4735x over previous
//
#include <hip/hip_runtime.h>
#include <stdint.h>

using short8 = __attribute__((ext_vector_type(8))) short;
using f32x4  = __attribute__((ext_vector_type(4))) float;
using u16x4  = __attribute__((ext_vector_type(4))) unsigned short;

__device__ __forceinline__ unsigned short f2bf(float f) {
    unsigned int u = __float_as_uint(f);
    unsigned int r = (u + 0x7fffu + ((u >> 16) & 1u)) >> 16;
    return (unsigned short)r;
}

// ---------------- wprep: B_all[off][col=rot*64+o][k=r*64+c] = wgt[o][c][(r-rot)&3][t(off,rot)] ----------------
__global__ __launch_bounds__(256) void k_wprep(const float* __restrict__ wgt,
                                               unsigned short* __restrict__ ball) {
    int idx = blockIdx.x * 256 + threadIdx.x;          // 589824 elems
    int k = idx & 255; int col = (idx >> 8) & 255; int j = idx >> 16;
    int rot = col >> 6, o = col & 63;
    int r = k >> 6, c = k & 63;
    int t = (j == 0) ? 0 : (1 + ((j - 1 - 2 * rot) & 7));
    float v = wgt[((o * 64 + c) * 4 + ((r - rot) & 3)) * 9 + t];
    ball[idx] = f2bf(v);
}

// ---------------- fused main: vectorized per-block transpose-stage, then R10 main loop ----------------
__global__ __launch_bounds__(512) void k_main(const float* __restrict__ x,
                                              const unsigned short* __restrict__ ball,
                                              float* __restrict__ out) {
    extern __shared__ char lds[];                      // 135168 A-panel + 17408 bounce = 152576
    int d = blockIdx.x;
    int orig = (d & 7) * 32 + (d >> 3);                // XCD-chunked: XCD x owns all h-blocks of n=x
    int n = orig >> 5; int h0 = (orig & 31) * 2;
    int tid = threadIdx.x;
    unsigned short* smu = (unsigned short*)(lds + 135168);   // bounce [128][68] u16 (68 => 8B-aligned rows)

    // zero the w-halo slots (ws=0, ws=65) of the A-panel
    if (tid < 256) {
        int r4 = tid >> 6; int sp = (tid >> 5) & 1; int cc = tid & 31;
        f32x4 z = {0.f, 0.f, 0.f, 0.f};
        *(f32x4*)(lds + r4 * 33792 + (sp ? 65 * 512 : 0) + cc * 16) = z;
    }

    // stage: transpose x[n][c][r][hh][w] -> A-panel, 4 rows x 2 k-halves
    int klA = tid >> 2; int wq = tid & 3;              // phase A: thread = (k-row, w-quarter)
#pragma unroll 1
    for (int r4 = 0; r4 < 4; r4++) {
        int hh = h0 - 1 + r4;
        bool ok = ((unsigned)hh < 64u);
#pragma unroll 1
        for (int half = 0; half < 2; half++) {
            // phase A: 128 k x 64 w -> bounce; float4 loads (16B/lane), b64 packed writes
            if (ok) {
                int k = half * 128 + klA;
                int r = k >> 6, c = k & 63;
                const float* src = x + (((size_t)(n * 64 + c) * 4 + r) * 64 + hh) * 64 + wq * 16;
#pragma unroll
                for (int i = 0; i < 4; i++) {
                    f32x4 v = *(const f32x4*)(src + i * 4);
                    u16x4 b; b[0] = f2bf(v[0]); b[1] = f2bf(v[1]);
                    b[2] = f2bf(v[2]); b[3] = f2bf(v[3]);
                    *(u16x4*)(smu + klA * 68 + wq * 16 + i * 4) = b;
                }
            } else {
                u16x4 z = {0, 0, 0, 0};
#pragma unroll
                for (int i = 0; i < 4; i++)
                    *(u16x4*)(smu + klA * 68 + wq * 16 + i * 4) = z;
            }
            __syncthreads();
            // phase B: repack k-major short8 chunks into swizzled A-panel (R10 pattern)
            {
                int w = tid & 63; int q = tid >> 6;
                int key = (w + 1) & 7;
                char* prow = lds + (r4 * 66 + (w + 1)) * 512;
#pragma unroll
                for (int ss = 0; ss < 2; ss++) {
                    int sl = q + ss * 8;               // 0..15
                    int sg = half * 16 + sl;           // global chunk: k = sg*8+e
                    short8 vv;
#pragma unroll
                    for (int e = 0; e < 8; e++) vv[e] = (short)smu[(sl * 8 + e) * 68 + w];
                    *(short8*)(prow + ((sg ^ key) << 4)) = vv;
                }
            }
            __syncthreads();
        }
    }

    // ---------------- main loop: R10-verbatim + setprio around MFMA clusters ----------------
    int wv = tid >> 6; int l = tid & 63; int l15 = l & 15; int l4 = l >> 4;
    int rot = wv >> 1;                                 // wave owns cols [wv*32, wv*32+32)
    const char* bb = (const char*)ball;

    for (int j = 0; j < 9; j++) {
        int dy = ((0x1A901 >> (2 * j)) & 3) - 1;
        int dx = ((0x01A91 >> (2 * j)) & 3) - 1;
        int t = (j == 0) ? 0 : (1 + ((j - 1 - 2 * rot) & 7));

        short8 Bf[2][8];
#pragma unroll
        for (int ct = 0; ct < 2; ct++) {
            int col = wv * 32 + ct * 16 + l15;
            const char* bp = bb + j * 131072 + col * 512 + l4 * 16;
#pragma unroll
            for (int ks = 0; ks < 8; ks++) Bf[ct][ks] = *(const short8*)(bp + ks * 64);
        }

#pragma unroll 1
        for (int mtp = 0; mtp < 4; mtp++) {
            short8 Af[2][8];
#pragma unroll
            for (int m2 = 0; m2 < 2; m2++) {
                int mt = mtp * 2 + m2;
                int pixel = mt * 16 + l15;
                int r4 = (pixel >> 6) + dy + 1;
                int ws = (pixel & 63) + dx + 1;
                const char* ap = lds + (r4 * 66 + ws) * 512;
                int key = ws & 7;
#pragma unroll
                for (int ks = 0; ks < 8; ks++) {
                    int s = ks * 4 + l4;
                    Af[m2][ks] = *(const short8*)(ap + ((s ^ key) << 4));
                }
            }
            f32x4 acc[2][2];
#pragma unroll
            for (int a = 0; a < 2; a++)
#pragma unroll
                for (int b2 = 0; b2 < 2; b2++) acc[a][b2] = (f32x4){0.f, 0.f, 0.f, 0.f};
            __builtin_amdgcn_s_setprio(1);
#pragma unroll
            for (int ks = 0; ks < 8; ks++)
#pragma unroll
                for (int ct = 0; ct < 2; ct++)
#pragma unroll
                    for (int m2 = 0; m2 < 2; m2++)
                        acc[ct][m2] = __builtin_amdgcn_mfma_f32_16x16x32_bf16(
                            Af[m2][ks], Bf[ct][ks], acc[ct][m2], 0, 0, 0);
            __builtin_amdgcn_s_setprio(0);
#pragma unroll
            for (int ct = 0; ct < 2; ct++) {
                int o = (wv & 1) * 32 + ct * 16 + l15;
#pragma unroll
                for (int m2 = 0; m2 < 2; m2++) {
                    int mt = mtp * 2 + m2;
                    int pb = mt * 16 + 4 * l4;
                    int h = h0 + (mt >> 2);
                    int wb = pb & 63;
                    int idx = (((n * 576 + t * 64 + o) * 4 + rot) * 64 + h) * 64 + wb;
                    *(f32x4*)(out + idx) = acc[ct][m2];
                }
            }
        }
    }
}

// ---------------- fallback (ws too small): direct fp32 ----------------
__global__ __launch_bounds__(256) void k_naive(const float* __restrict__ x,
                                               const float* __restrict__ wgt,
                                               float* __restrict__ out) {
    int idx = blockIdx.x * 256 + threadIdx.x;
    if (idx >= 75497472) return;
    int w = idx & 63, h = (idx >> 6) & 63, rot = (idx >> 12) & 3;
    int chn = idx >> 14; int ch = chn % 576; int n = chn / 576;
    int t = ch >> 6, o = ch & 63;
    int dy = 0, dx = 0;
    if (t > 0) {
        int ri = (t - 1 + 2 * rot) & 7;
        dy = ((27200 >> (2 * ri)) & 3) - 1;
        dx = ((1700 >> (2 * ri)) & 3) - 1;
    }
    int hh = h + dy, ww = w + dx;
    float acc = 0.f;
    if (hh >= 0 && hh < 64 && ww >= 0 && ww < 64) {
        for (int r = 0; r < 4; r++) {
            int rr = (r - rot) & 3;
            for (int c = 0; c < 64; c++)
                acc += x[(((n * 64 + c) * 4 + r) * 64 + hh) * 64 + ww] *
                       wgt[((o * 64 + c) * 4 + rr) * 9 + t];
        }
    }
    out[idx] = acc;
}

extern "C" void kernel_launch(void* const* d_in, const int* in_sizes, int n_in,
                              void* d_out, int out_size, void* d_ws, size_t ws_size,
                              hipStream_t stream) {
    const float* x = (const float*)d_in[0];
    const float* wgt = (const float*)d_in[1];
    float* out = (float*)d_out;
    const size_t NEED = (size_t)9 * 256 * 256 * 2;     // 1,179,648 (ball only)
    if (ws_size < NEED) {
        k_naive<<<(75497472 + 255) / 256, 256, 0, stream>>>(x, wgt, out);
        return;
    }
    unsigned short* ball = (unsigned short*)d_ws;
    k_wprep<<<2304, 256, 0, stream>>>(wgt, ball);
    k_main<<<256, 512, 152576, stream>>>(x, ball, out);
}